// Round 7
// baseline (663.747 us; speedup 1.0000x reference)
//
#include <hip/hip_runtime.h>
#include <math.h>

#define NCH 48
#define NB 16
#define PLANE 16384
#define NPLANES 768

// d_ws float layout
#define WS_PSUM  0
#define WS_PSQ   768
#define WS_SCALE 1536
#define WS_SHIFT 1584
#define WS_TAB   1632   // [src 4][tgt 4][6 coefs]
#define WS_CONST 1728   // [4]

// compile-time for: every per-thread array index is a literal (rule #20)
template<int I> struct ic { static constexpr int v = I; };
template<int S, int E, typename F>
__device__ __forceinline__ void sfor(F&& f) {
  if constexpr (S < E) { f(ic<S>{}); sfor<S + 1, E>(f); }
}

typedef float f16v __attribute__((ext_vector_type(16)));

// ---------------- stage A: per-plane partial sums ----------------
__global__ __launch_bounds__(256) void stats_kernel(const float* __restrict__ x,
                                                    float* __restrict__ ws) {
  int p = blockIdx.x;
  int t = threadIdx.x;
  const float4* x4 = (const float4*)x + (size_t)p * 4096;
  float s = 0.f, q = 0.f;
  #pragma unroll
  for (int k = 0; k < 16; ++k) {
    float4 v = x4[k * 256 + t];
    s += v.x + v.y + v.z + v.w;
    q += v.x * v.x + v.y * v.y + v.z * v.z + v.w * v.w;
  }
  #pragma unroll
  for (int off = 32; off > 0; off >>= 1) {
    s += __shfl_xor(s, off, 64);
    q += __shfl_xor(q, off, 64);
  }
  __shared__ float red[8];
  int wid = t >> 6, lane = t & 63;
  if (lane == 0) { red[wid] = s; red[4 + wid] = q; }
  __syncthreads();
  if (t == 0) {
    ws[WS_PSUM + p] = red[0] + red[1] + red[2] + red[3];
    ws[WS_PSQ  + p] = red[4] + red[5] + red[6] + red[7];
  }
}

// ---------------- stage B: BN params + merged weight table ----------------
__global__ void prep_kernel(const float* __restrict__ gamma, const float* __restrict__ beta,
                            const float* __restrict__ alphas, float* __restrict__ ws) {
  int t = threadIdx.x;
  if (t < NCH) {
    float s = 0.f, q = 0.f;
    for (int b = 0; b < NB; ++b) {
      s += ws[WS_PSUM + b * NCH + t];
      q += ws[WS_PSQ  + b * NCH + t];
    }
    const float inv = 1.0f / ((float)NB * PLANE);
    float mean = s * inv;
    float var  = q * inv - mean * mean;
    float sc = gamma[t] * rsqrtf(var + 1e-5f);
    ws[WS_SCALE + t] = sc;
    ws[WS_SHIFT + t] = beta[t] - mean * sc;
  }
  if (t == 0) {
    float w[14][7];
    for (int r = 0; r < 14; ++r) {
      float m = -1e30f;
      for (int k = 0; k < 7; ++k) m = fmaxf(m, alphas[r * 7 + k]);
      float sum = 0.f;
      for (int k = 0; k < 7; ++k) { float e = expf(alphas[r * 7 + k] - m); w[r][k] = e; sum += e; }
      float is = 1.0f / sum;
      for (int k = 0; k < 7; ++k) w[r][k] *= is;
    }
    for (int i = 0; i < 96; ++i) ws[WS_TAB + i] = 0.f;
    for (int i = 0; i < 4;  ++i) ws[WS_CONST + i] = 0.f;
    const int map[14][2] = {
      {0,0},{0,0},
      {0,1},{0,1},{1,1},
      {0,2},{0,2},{1,2},{2,2},
      {0,3},{0,3},{1,3},{2,3},{3,3}
    };
    for (int r = 0; r < 14; ++r) {
      int p = map[r][0], tg = map[r][1];
      float* cf = ws + WS_TAB + (p * 4 + tg) * 6;
      cf[0] += w[r][0] - w[r][2];       // identity
      cf[1] += w[r][1] * (1.0f / 9.0f); // blur (/9 folded)
      cf[2] += w[r][3];                 // fliplr
      cf[3] += w[r][4];                 // flipud
      cf[4] += w[r][5];                 // roll(+4,+4)
      cf[5] += w[r][6];                 // rot90
      ws[WS_CONST + tg] += w[r][2];     // constant w2
    }
  }
}

// ---------------- main fused kernel ----------------
// LDS swizzle: float4-block index for (row i, block bj): bj ^= (i>>2)&7.
__device__ __forceinline__ int swb(int i, int bj) {
  return (i << 5) + (bj ^ ((i >> 2) & 7));
}
__device__ __forceinline__ float ldsw(const float* l, int i, int j) {
  int bj = j >> 2;
  return l[(i << 7) + (((bj ^ ((i >> 2) & 7)) << 2) | (j & 3))];
}

__device__ __forceinline__ void ldcf(float (&cf)[6], const float* __restrict__ wsf,
                                     int p, int tg) {
  sfor<0, 6>([&](auto K) { cf[K.v] = wsf[WS_TAB + (p * 4 + tg) * 6 + K.v]; });
}

// Single-target full-plane gather: 6-op linear stencil from LDS into T.
// Only 16 accumulator floats live — fits the 64-VGPR budget the backend
// insists on (R2-R6: every multi-acc variant spilled ~1 GB to scratch).
__device__ __forceinline__ void gather(const float4* l4, const float* l1,
    int oi, int oj, int ty, int tx, const float (&cf)[6], f16v& T)
{
  // ---- identity + box blur (6 rows, reflect borders) ----
  int cLo = (tx == 0)  ? 1   : oj - 1;
  int cHi = (tx == 31) ? 126 : oj + 4;
  float hs[3][4];
  sfor<0, 6>([&](auto RC) {
    constexpr int r = RC.v;
    int ri = oi - 1 + r;
    ri = (ri < 0) ? 1 : ((ri > 127) ? 126 : ri);
    float4 mid = l4[swb(ri, tx)];
    float lo = ldsw(l1, ri, cLo);
    float hi = ldsw(l1, ri, cHi);
    if constexpr (r >= 1 && r <= 4) {
      constexpr int a = r - 1;
      T[a * 4 + 0] += cf[0] * mid.x;
      T[a * 4 + 1] += cf[0] * mid.y;
      T[a * 4 + 2] += cf[0] * mid.z;
      T[a * 4 + 3] += cf[0] * mid.w;
    }
    hs[r % 3][0] = lo    + mid.x + mid.y;
    hs[r % 3][1] = mid.x + mid.y + mid.z;
    hs[r % 3][2] = mid.y + mid.z + mid.w;
    hs[r % 3][3] = mid.z + mid.w + hi;
    if constexpr (r >= 2) {
      constexpr int a = r - 2;
      sfor<0, 4>([&](auto QC) {
        constexpr int bq = QC.v;
        T[a * 4 + bq] += cf[1] * (hs[0][bq] + hs[1][bq] + hs[2][bq]);
      });
    }
  });
  // ---- fliplr ----
  sfor<0, 4>([&](auto AC) {
    constexpr int a = AC.v;
    float4 m = l4[swb(oi + a, 31 - tx)];
    T[a * 4 + 0] += cf[2] * m.w;
    T[a * 4 + 1] += cf[2] * m.z;
    T[a * 4 + 2] += cf[2] * m.y;
    T[a * 4 + 3] += cf[2] * m.x;
  });
  // ---- flipud ----
  sfor<0, 4>([&](auto AC) {
    constexpr int a = AC.v;
    float4 m = l4[swb(127 - oi - a, tx)];
    T[a * 4 + 0] += cf[3] * m.x;
    T[a * 4 + 1] += cf[3] * m.y;
    T[a * 4 + 2] += cf[3] * m.z;
    T[a * 4 + 3] += cf[3] * m.w;
  });
  // ---- roll(+4,+4) ----
  sfor<0, 4>([&](auto AC) {
    constexpr int a = AC.v;
    float4 m = l4[swb((oi + a - 4) & 127, (tx + 31) & 31)];
    T[a * 4 + 0] += cf[4] * m.x;
    T[a * 4 + 1] += cf[4] * m.y;
    T[a * 4 + 2] += cf[4] * m.z;
    T[a * 4 + 3] += cf[4] * m.w;
  });
  // ---- rot90 (k=1): out[i][j] = src[j][127-i] ----
  sfor<0, 4>([&](auto RB) {
    constexpr int rb = RB.v;
    float4 m = l4[swb(oj + rb, 31 - ty)];
    T[ 0 + rb] += cf[5] * m.w;
    T[ 4 + rb] += cf[5] * m.z;
    T[ 8 + rb] += cf[5] * m.y;
    T[12 + rb] += cf[5] * m.x;
  });
}

// Sequential-target schedule: one f16v accumulator ever live. Finished
// states are re-read from global out (same block wrote them; __syncthreads
// orders block-level global accesses) — L2/L3-hot, ~50 MB each.
__global__ __launch_bounds__(1024)
void main_kernel(const float* __restrict__ x,
                 const float* __restrict__ wsf, float* out)
{
  __shared__ float lds[2 * PLANE];        // 128 KB -> 1 block/CU
  float* b0 = lds;
  float* b1 = lds + PLANE;
  float4* l40 = (float4*)b0;
  float4* l41 = (float4*)b1;
  int bx = blockIdx.x;
  int b = bx / NCH, c = bx % NCH;
  int tid = threadIdx.x;
  int ty = tid >> 5, tx = tid & 31;
  int oi = ty << 2, oj = tx << 2;
  float4* out4 = (float4*)out;
  const size_t pbase = (size_t)b * 192 + c;
  const float4* x4 = (const float4*)x + (size_t)bx * 4096;
  float sc = wsf[WS_SCALE + c], sh = wsf[WS_SHIFT + c];

  float cf[6];
  f16v T;

  // helpers (macros keep everything constexpr-indexed)
#define STAGE_BN(L4)                                                           \
  sfor<0, 4>([&](auto RC) {                                                    \
    constexpr int r = RC.v;                                                    \
    float4 v = x4[(oi + r) * 32 + tx];                                         \
    float4 sv;                                                                 \
    sv.x = v.x * sc + sh; sv.y = v.y * sc + sh;                                \
    sv.z = v.z * sc + sh; sv.w = v.w * sc + sh;                                \
    L4[swb(oi + r, tx)] = sv;                                                  \
  })
#define STAGE_OUT(L4, TG)                                                      \
  sfor<0, 4>([&](auto RC) {                                                    \
    constexpr int r = RC.v;                                                    \
    float4 v = out4[(pbase + TG * NCH) * 4096 + (oi + r) * 32 + tx];           \
    L4[swb(oi + r, tx)] = v;                                                   \
  })
#define WRITEV(TG)                                                             \
  sfor<0, 4>([&](auto RC) {                                                    \
    constexpr int r = RC.v;                                                    \
    float4 v; v.x = T[r*4+0]; v.y = T[r*4+1]; v.z = T[r*4+2]; v.w = T[r*4+3];  \
    out4[(pbase + TG * NCH) * 4096 + (oi + r) * 32 + tx] = v;                  \
  })
#define STASHV(L4)                                                             \
  sfor<0, 4>([&](auto RC) {                                                    \
    constexpr int r = RC.v;                                                    \
    float4 v; v.x = T[r*4+0]; v.y = T[r*4+1]; v.z = T[r*4+2]; v.w = T[r*4+3];  \
    L4[swb(oi + r, tx)] = v;                                                   \
  })
#define SETC(K) { float cst = wsf[WS_CONST + K]; sfor<0, 16>([&](auto KC) { T[KC.v] = cst; }); }

  // stage s -> buf0
  STAGE_BN(l40);
  __syncthreads();

  // ---- s2 = L(0,0)[s] ----
  SETC(0);
  ldcf(cf, wsf, 0, 0);
  gather(l40, b0, oi, oj, ty, tx, cf, T);
  WRITEV(0);
  STASHV(l41);                 // s2 -> buf1 (no prior readers of buf1)
  __syncthreads();

  // ---- s3 = L(0,1)[s] + L(1,1)[s2] ----
  SETC(1);
  ldcf(cf, wsf, 0, 1);
  gather(l40, b0, oi, oj, ty, tx, cf, T);
  ldcf(cf, wsf, 1, 1);
  gather(l41, b1, oi, oj, ty, tx, cf, T);
  WRITEV(1);

  // ---- s4 = L(0,2)[s] + L(1,2)[s2] + L(2,2)[s3] ----
  SETC(2);
  ldcf(cf, wsf, 0, 2);
  gather(l40, b0, oi, oj, ty, tx, cf, T);
  ldcf(cf, wsf, 1, 2);
  gather(l41, b1, oi, oj, ty, tx, cf, T);
  __syncthreads();             // buf0 reads done; s3 global writes visible
  STAGE_OUT(l40, 1);           // s3 -> buf0
  __syncthreads();
  ldcf(cf, wsf, 2, 2);
  gather(l40, b0, oi, oj, ty, tx, cf, T);
  WRITEV(2);

  // ---- s5 = L(0,3)[s] + L(1,3)[s2] + L(2,3)[s3] + L(3,3)[s4] ----
  SETC(3);
  ldcf(cf, wsf, 2, 3);
  gather(l40, b0, oi, oj, ty, tx, cf, T);   // s3 still in buf0
  ldcf(cf, wsf, 1, 3);
  gather(l41, b1, oi, oj, ty, tx, cf, T);   // s2 still in buf1
  __syncthreads();             // all buffer reads done; s4 writes visible
  STAGE_OUT(l41, 2);           // s4 -> buf1
  STAGE_BN(l40);               // s  -> buf0 (re-BN from x, L3-hot)
  __syncthreads();
  ldcf(cf, wsf, 3, 3);
  gather(l41, b1, oi, oj, ty, tx, cf, T);
  ldcf(cf, wsf, 0, 3);
  gather(l40, b0, oi, oj, ty, tx, cf, T);
  WRITEV(3);
}

extern "C" void kernel_launch(void* const* d_in, const int* in_sizes, int n_in,
                              void* d_out, int out_size, void* d_ws, size_t ws_size,
                              hipStream_t stream) {
  (void)in_sizes; (void)n_in; (void)out_size; (void)ws_size;
  const float* x     = (const float*)d_in[0];
  const float* gamma = (const float*)d_in[1];
  const float* beta  = (const float*)d_in[2];
  const float* a_red = (const float*)d_in[4];   // reference uses alphas_reduce
  float* ws  = (float*)d_ws;
  float* out = (float*)d_out;

  stats_kernel<<<NPLANES, 256, 0, stream>>>(x, ws);
  prep_kernel<<<1, 64, 0, stream>>>(gamma, beta, a_red, ws);
  main_kernel<<<NPLANES, 1024, 0, stream>>>(x, ws, out);
}

// Round 8
// 371.953 us; speedup vs baseline: 1.7845x; 1.7845x over previous
//
#include <hip/hip_runtime.h>
#include <math.h>

#define NCH 48
#define NB 16
#define PLANE 16384
#define NPLANES 768

// d_ws float layout
#define WS_PSUM  0
#define WS_PSQ   768
#define WS_SCALE 1536
#define WS_SHIFT 1584
#define WS_TAB   1632   // [src 4][tgt 4][6 coefs]
#define WS_CONST 1728   // [4]

// ---------------- stage A: per-plane partial sums ----------------
__global__ __launch_bounds__(256) void stats_kernel(const float* __restrict__ x,
                                                    float* __restrict__ ws) {
  int p = blockIdx.x;
  int t = threadIdx.x;
  const float4* x4 = (const float4*)x + (size_t)p * 4096;
  float s = 0.f, q = 0.f;
  #pragma unroll
  for (int k = 0; k < 16; ++k) {
    float4 v = x4[k * 256 + t];
    s += v.x + v.y + v.z + v.w;
    q += v.x * v.x + v.y * v.y + v.z * v.z + v.w * v.w;
  }
  #pragma unroll
  for (int off = 32; off > 0; off >>= 1) {
    s += __shfl_xor(s, off, 64);
    q += __shfl_xor(q, off, 64);
  }
  __shared__ float red[8];
  int wid = t >> 6, lane = t & 63;
  if (lane == 0) { red[wid] = s; red[4 + wid] = q; }
  __syncthreads();
  if (t == 0) {
    ws[WS_PSUM + p] = red[0] + red[1] + red[2] + red[3];
    ws[WS_PSQ  + p] = red[4] + red[5] + red[6] + red[7];
  }
}

// ---------------- stage B: BN params + merged weight table ----------------
__global__ void prep_kernel(const float* __restrict__ gamma, const float* __restrict__ beta,
                            const float* __restrict__ alphas, float* __restrict__ ws) {
  int t = threadIdx.x;
  if (t < NCH) {
    float s = 0.f, q = 0.f;
    for (int b = 0; b < NB; ++b) {
      s += ws[WS_PSUM + b * NCH + t];
      q += ws[WS_PSQ  + b * NCH + t];
    }
    const float inv = 1.0f / ((float)NB * PLANE);
    float mean = s * inv;
    float var  = q * inv - mean * mean;
    float sc = gamma[t] * rsqrtf(var + 1e-5f);
    ws[WS_SCALE + t] = sc;
    ws[WS_SHIFT + t] = beta[t] - mean * sc;
  }
  if (t == 0) {
    float w[14][7];
    for (int r = 0; r < 14; ++r) {
      float m = -1e30f;
      for (int k = 0; k < 7; ++k) m = fmaxf(m, alphas[r * 7 + k]);
      float sum = 0.f;
      for (int k = 0; k < 7; ++k) { float e = expf(alphas[r * 7 + k] - m); w[r][k] = e; sum += e; }
      float is = 1.0f / sum;
      for (int k = 0; k < 7; ++k) w[r][k] *= is;
    }
    for (int i = 0; i < 96; ++i) ws[WS_TAB + i] = 0.f;
    for (int i = 0; i < 4;  ++i) ws[WS_CONST + i] = 0.f;
    const int map[14][2] = {
      {0,0},{0,0},
      {0,1},{0,1},{1,1},
      {0,2},{0,2},{1,2},{2,2},
      {0,3},{0,3},{1,3},{2,3},{3,3}
    };
    for (int r = 0; r < 14; ++r) {
      int p = map[r][0], tg = map[r][1];
      float* cf = ws + WS_TAB + (p * 4 + tg) * 6;
      cf[0] += w[r][0] - w[r][2];       // identity
      cf[1] += w[r][1] * (1.0f / 9.0f); // blur (/9 folded)
      cf[2] += w[r][3];                 // fliplr
      cf[3] += w[r][4];                 // flipud
      cf[4] += w[r][5];                 // roll(+4,+4)
      cf[5] += w[r][6];                 // rot90
      ws[WS_CONST + tg] += w[r][2];     // constant w2
    }
  }
}

// ---------------- main fused kernel ----------------
// LDS swizzle: float4-block index for (row i, block bj): bj ^= (i>>2)&7.
__device__ __forceinline__ int swb(int i, int bj) {
  return (i << 5) + (bj ^ ((i >> 2) & 7));
}
__device__ __forceinline__ float ldsw(const float* l, int i, int j) {
  int bj = j >> 2;
  return l[(i << 7) + (((bj ^ ((i >> 2) & 7)) << 2) | (j & 3))];
}

// NO per-thread arrays, NO lambdas anywhere below (R5-R7 post-mortem: the
// sfor-lambda / unrolled-array pattern left acc+temps as memory allocas ->
// every acc update round-tripped scratch, ~120 MB HBM per gather pass).
// Everything is named float4 scalars expanded via plain macros.

#define HROW(h, m, lo, hi)                                                     \
  h.x = lo + m.x + m.y; h.y = m.x + m.y + m.z;                                 \
  h.z = m.y + m.z + m.w; h.w = m.z + m.w + hi;

#define FMA4(T, C, M)                                                          \
  T.x += (C) * M.x; T.y += (C) * M.y; T.z += (C) * M.z; T.w += (C) * M.w;

#define BLUR4(T, A, B, Cq)                                                     \
  T.x += c1 * (A.x + B.x + Cq.x); T.y += c1 * (A.y + B.y + Cq.y);              \
  T.z += c1 * (A.z + B.z + Cq.z); T.w += c1 * (A.w + B.w + Cq.w);

#define FLIPL(T, M)                                                            \
  T.x += c2 * M.w; T.y += c2 * M.z; T.z += c2 * M.y; T.w += c2 * M.x;

// full-plane 6-op linear stencil from LDS buffer (L4/L1 views) into T0..T3
#define GATHER(L4, L1) {                                                       \
  float4 m, hA, hB, hC; float lo, hi; int ri;                                  \
  /* r=0 */                                                                    \
  ri = (oi == 0) ? 1 : oi - 1;                                                 \
  m = (L4)[swb(ri, tx)]; lo = ldsw((L1), ri, cLo); hi = ldsw((L1), ri, cHi);   \
  HROW(hA, m, lo, hi)                                                          \
  /* r=1 */                                                                    \
  m = (L4)[swb(oi, tx)]; lo = ldsw((L1), oi, cLo); hi = ldsw((L1), oi, cHi);   \
  FMA4(T0, c0, m)                                                              \
  HROW(hB, m, lo, hi)                                                          \
  /* r=2 */                                                                    \
  m = (L4)[swb(oi+1, tx)]; lo = ldsw((L1), oi+1, cLo); hi = ldsw((L1), oi+1, cHi); \
  FMA4(T1, c0, m)                                                              \
  HROW(hC, m, lo, hi)                                                          \
  BLUR4(T0, hA, hB, hC)                                                        \
  /* r=3 */                                                                    \
  m = (L4)[swb(oi+2, tx)]; lo = ldsw((L1), oi+2, cLo); hi = ldsw((L1), oi+2, cHi); \
  FMA4(T2, c0, m)                                                              \
  HROW(hA, m, lo, hi)                                                          \
  BLUR4(T1, hB, hC, hA)                                                        \
  /* r=4 */                                                                    \
  m = (L4)[swb(oi+3, tx)]; lo = ldsw((L1), oi+3, cLo); hi = ldsw((L1), oi+3, cHi); \
  FMA4(T3, c0, m)                                                              \
  HROW(hB, m, lo, hi)                                                          \
  BLUR4(T2, hC, hA, hB)                                                        \
  /* r=5 */                                                                    \
  ri = (oi == 124) ? 126 : oi + 4;                                             \
  m = (L4)[swb(ri, tx)]; lo = ldsw((L1), ri, cLo); hi = ldsw((L1), ri, cHi);   \
  HROW(hC, m, lo, hi)                                                          \
  BLUR4(T3, hA, hB, hC)                                                        \
  /* fliplr: out[i][j] = src[i][127-j] */                                      \
  m = (L4)[swb(oi,   31 - tx)]; FLIPL(T0, m)                                   \
  m = (L4)[swb(oi+1, 31 - tx)]; FLIPL(T1, m)                                   \
  m = (L4)[swb(oi+2, 31 - tx)]; FLIPL(T2, m)                                   \
  m = (L4)[swb(oi+3, 31 - tx)]; FLIPL(T3, m)                                   \
  /* flipud: out[i][j] = src[127-i][j] */                                      \
  m = (L4)[swb(127 - oi, tx)]; FMA4(T0, c3, m)                                 \
  m = (L4)[swb(126 - oi, tx)]; FMA4(T1, c3, m)                                 \
  m = (L4)[swb(125 - oi, tx)]; FMA4(T2, c3, m)                                 \
  m = (L4)[swb(124 - oi, tx)]; FMA4(T3, c3, m)                                 \
  /* roll(+4,+4): out[i][j] = src[(i-4)&127][(j-4)&127] */                     \
  m = (L4)[swb((oi - 4) & 127, rc)]; FMA4(T0, c4, m)                           \
  m = (L4)[swb((oi - 3) & 127, rc)]; FMA4(T1, c4, m)                           \
  m = (L4)[swb((oi - 2) & 127, rc)]; FMA4(T2, c4, m)                           \
  m = (L4)[swb((oi - 1) & 127, rc)]; FMA4(T3, c4, m)                           \
  /* rot90 k=1: out[i][j] = src[j][127-i]; word 3-a of block 31-ty is row oi+a */ \
  m = (L4)[swb(oj,     31 - ty)];                                              \
  T0.x += c5 * m.w; T1.x += c5 * m.z; T2.x += c5 * m.y; T3.x += c5 * m.x;      \
  m = (L4)[swb(oj + 1, 31 - ty)];                                              \
  T0.y += c5 * m.w; T1.y += c5 * m.z; T2.y += c5 * m.y; T3.y += c5 * m.x;      \
  m = (L4)[swb(oj + 2, 31 - ty)];                                              \
  T0.z += c5 * m.w; T1.z += c5 * m.z; T2.z += c5 * m.y; T3.z += c5 * m.x;      \
  m = (L4)[swb(oj + 3, 31 - ty)];                                              \
  T0.w += c5 * m.w; T1.w += c5 * m.z; T2.w += c5 * m.y; T3.w += c5 * m.x;      \
}

#define LDCF(P, TG) {                                                          \
  const float* cfp = wsf + WS_TAB + ((P) * 4 + (TG)) * 6;                      \
  c0 = cfp[0]; c1 = cfp[1]; c2 = cfp[2]; c3 = cfp[3]; c4 = cfp[4]; c5 = cfp[5]; }

#define SETC(K) {                                                              \
  float cst = wsf[WS_CONST + (K)];                                             \
  T0.x = cst; T0.y = cst; T0.z = cst; T0.w = cst; T1 = T0; T2 = T0; T3 = T0; }

#define STAGE_BN(L4) {                                                         \
  float4 v;                                                                    \
  v = x4[(oi+0)*32 + tx]; v.x = v.x*sc+sh; v.y = v.y*sc+sh; v.z = v.z*sc+sh;   \
  v.w = v.w*sc+sh; (L4)[swb(oi+0, tx)] = v;                                    \
  v = x4[(oi+1)*32 + tx]; v.x = v.x*sc+sh; v.y = v.y*sc+sh; v.z = v.z*sc+sh;   \
  v.w = v.w*sc+sh; (L4)[swb(oi+1, tx)] = v;                                    \
  v = x4[(oi+2)*32 + tx]; v.x = v.x*sc+sh; v.y = v.y*sc+sh; v.z = v.z*sc+sh;   \
  v.w = v.w*sc+sh; (L4)[swb(oi+2, tx)] = v;                                    \
  v = x4[(oi+3)*32 + tx]; v.x = v.x*sc+sh; v.y = v.y*sc+sh; v.z = v.z*sc+sh;   \
  v.w = v.w*sc+sh; (L4)[swb(oi+3, tx)] = v; }

#define STAGE_OUT(L4, TG) {                                                    \
  (L4)[swb(oi+0, tx)] = out4[(pbase + (TG)*NCH)*4096 + (oi+0)*32 + tx];        \
  (L4)[swb(oi+1, tx)] = out4[(pbase + (TG)*NCH)*4096 + (oi+1)*32 + tx];        \
  (L4)[swb(oi+2, tx)] = out4[(pbase + (TG)*NCH)*4096 + (oi+2)*32 + tx];        \
  (L4)[swb(oi+3, tx)] = out4[(pbase + (TG)*NCH)*4096 + (oi+3)*32 + tx]; }

#define WRITEV(TG) {                                                           \
  out4[(pbase + (TG)*NCH)*4096 + (oi+0)*32 + tx] = T0;                         \
  out4[(pbase + (TG)*NCH)*4096 + (oi+1)*32 + tx] = T1;                         \
  out4[(pbase + (TG)*NCH)*4096 + (oi+2)*32 + tx] = T2;                         \
  out4[(pbase + (TG)*NCH)*4096 + (oi+3)*32 + tx] = T3; }

#define STASHV(L4) {                                                           \
  (L4)[swb(oi+0, tx)] = T0; (L4)[swb(oi+1, tx)] = T1;                          \
  (L4)[swb(oi+2, tx)] = T2; (L4)[swb(oi+3, tx)] = T3; }

__global__ __launch_bounds__(1024)
void main_kernel(const float* __restrict__ x,
                 const float* __restrict__ wsf, float* out)
{
  __shared__ float lds[2 * PLANE];        // 128 KB -> 1 block/CU
  float* b0 = lds;
  float* b1 = lds + PLANE;
  float4* l40 = (float4*)b0;
  float4* l41 = (float4*)b1;
  int bx = blockIdx.x;
  int b = bx / NCH, c = bx % NCH;
  int tid = threadIdx.x;
  int ty = tid >> 5, tx = tid & 31;
  int oi = ty << 2, oj = tx << 2;
  int cLo = (tx == 0)  ? 1   : oj - 1;
  int cHi = (tx == 31) ? 126 : oj + 4;
  int rc  = (tx + 31) & 31;
  float4* out4 = (float4*)out;
  const size_t pbase = (size_t)b * 192 + c;
  const float4* x4 = (const float4*)x + (size_t)bx * 4096;
  float sc = wsf[WS_SCALE + c], sh = wsf[WS_SHIFT + c];

  float4 T0, T1, T2, T3;
  float c0, c1, c2, c3, c4, c5;

  // stage s -> buf0
  STAGE_BN(l40);
  __syncthreads();

  // ---- s2 = L(0,0)[s] ----
  SETC(0);
  LDCF(0, 0);
  GATHER(l40, b0);
  WRITEV(0);
  STASHV(l41);                 // s2 -> buf1
  __syncthreads();

  // ---- s3 = L(0,1)[s] + L(1,1)[s2] ----
  SETC(1);
  LDCF(0, 1);
  GATHER(l40, b0);
  LDCF(1, 1);
  GATHER(l41, b1);
  WRITEV(1);

  // ---- s4 = L(0,2)[s] + L(1,2)[s2] + L(2,2)[s3] ----
  SETC(2);
  LDCF(0, 2);
  GATHER(l40, b0);
  LDCF(1, 2);
  GATHER(l41, b1);
  __syncthreads();             // buf0 reads done; s3 global writes visible
  STAGE_OUT(l40, 1);           // s3 -> buf0
  __syncthreads();
  LDCF(2, 2);
  GATHER(l40, b0);
  WRITEV(2);

  // ---- s5 = L(0,3)[s] + L(1,3)[s2] + L(2,3)[s3] + L(3,3)[s4] ----
  SETC(3);
  LDCF(2, 3);
  GATHER(l40, b0);             // s3 still in buf0
  LDCF(1, 3);
  GATHER(l41, b1);             // s2 still in buf1
  __syncthreads();             // all buffer reads done; s4 writes visible
  STAGE_OUT(l41, 2);           // s4 -> buf1
  STAGE_BN(l40);               // s  -> buf0 (re-BN from x, L3-hot)
  __syncthreads();
  LDCF(3, 3);
  GATHER(l41, b1);
  LDCF(0, 3);
  GATHER(l40, b0);
  WRITEV(3);
}

extern "C" void kernel_launch(void* const* d_in, const int* in_sizes, int n_in,
                              void* d_out, int out_size, void* d_ws, size_t ws_size,
                              hipStream_t stream) {
  (void)in_sizes; (void)n_in; (void)out_size; (void)ws_size;
  const float* x     = (const float*)d_in[0];
  const float* gamma = (const float*)d_in[1];
  const float* beta  = (const float*)d_in[2];
  const float* a_red = (const float*)d_in[4];   // reference uses alphas_reduce
  float* ws  = (float*)d_ws;
  float* out = (float*)d_out;

  stats_kernel<<<NPLANES, 256, 0, stream>>>(x, ws);
  prep_kernel<<<1, 64, 0, stream>>>(gamma, beta, a_red, ws);
  main_kernel<<<NPLANES, 1024, 0, stream>>>(x, ws, out);
}

// Round 9
// 167.957 us; speedup vs baseline: 3.9519x; 2.2146x over previous
//
#include <hip/hip_runtime.h>
#include <math.h>

#define NCH 48
#define NB 16
#define PLANE 16384
#define NPLANES 768

// d_ws float layout
#define WS_PSUM  0
#define WS_PSQ   768
#define WS_SCALE 1536
#define WS_SHIFT 1584
#define WS_TAB   1632   // [src 4][tgt 4][6 coefs]
#define WS_CONST 1728   // [4]

// ---------------- stage A: per-plane partial sums ----------------
__global__ __launch_bounds__(256) void stats_kernel(const float* __restrict__ x,
                                                    float* __restrict__ ws) {
  int p = blockIdx.x;
  int t = threadIdx.x;
  const float4* x4 = (const float4*)x + (size_t)p * 4096;
  float s = 0.f, q = 0.f;
  #pragma unroll
  for (int k = 0; k < 16; ++k) {
    float4 v = x4[k * 256 + t];
    s += v.x + v.y + v.z + v.w;
    q += v.x * v.x + v.y * v.y + v.z * v.z + v.w * v.w;
  }
  #pragma unroll
  for (int off = 32; off > 0; off >>= 1) {
    s += __shfl_xor(s, off, 64);
    q += __shfl_xor(q, off, 64);
  }
  __shared__ float red[8];
  int wid = t >> 6, lane = t & 63;
  if (lane == 0) { red[wid] = s; red[4 + wid] = q; }
  __syncthreads();
  if (t == 0) {
    ws[WS_PSUM + p] = red[0] + red[1] + red[2] + red[3];
    ws[WS_PSQ  + p] = red[4] + red[5] + red[6] + red[7];
  }
}

// ---------------- stage B: BN params + merged weight table ----------------
__global__ void prep_kernel(const float* __restrict__ gamma, const float* __restrict__ beta,
                            const float* __restrict__ alphas, float* __restrict__ ws) {
  int t = threadIdx.x;
  if (t < NCH) {
    float s = 0.f, q = 0.f;
    for (int b = 0; b < NB; ++b) {
      s += ws[WS_PSUM + b * NCH + t];
      q += ws[WS_PSQ  + b * NCH + t];
    }
    const float inv = 1.0f / ((float)NB * PLANE);
    float mean = s * inv;
    float var  = q * inv - mean * mean;
    float sc = gamma[t] * rsqrtf(var + 1e-5f);
    ws[WS_SCALE + t] = sc;
    ws[WS_SHIFT + t] = beta[t] - mean * sc;
  }
  if (t == 0) {
    float w[14][7];
    for (int r = 0; r < 14; ++r) {
      float m = -1e30f;
      for (int k = 0; k < 7; ++k) m = fmaxf(m, alphas[r * 7 + k]);
      float sum = 0.f;
      for (int k = 0; k < 7; ++k) { float e = expf(alphas[r * 7 + k] - m); w[r][k] = e; sum += e; }
      float is = 1.0f / sum;
      for (int k = 0; k < 7; ++k) w[r][k] *= is;
    }
    for (int i = 0; i < 96; ++i) ws[WS_TAB + i] = 0.f;
    for (int i = 0; i < 4;  ++i) ws[WS_CONST + i] = 0.f;
    const int map[14][2] = {
      {0,0},{0,0},
      {0,1},{0,1},{1,1},
      {0,2},{0,2},{1,2},{2,2},
      {0,3},{0,3},{1,3},{2,3},{3,3}
    };
    for (int r = 0; r < 14; ++r) {
      int p = map[r][0], tg = map[r][1];
      float* cf = ws + WS_TAB + (p * 4 + tg) * 6;
      cf[0] += w[r][0] - w[r][2];       // identity
      cf[1] += w[r][1] * (1.0f / 9.0f); // blur (/9 folded)
      cf[2] += w[r][3];                 // fliplr
      cf[3] += w[r][4];                 // flipud
      cf[4] += w[r][5];                 // roll(+4,+4)
      cf[5] += w[r][6];                 // rot90
      ws[WS_CONST + tg] += w[r][2];     // constant w2
    }
  }
}

// ---------------- main fused kernel ----------------
// LDS swizzle: float4-block index for (row i, block bj): bj ^= (i>>2)&7.
__device__ __forceinline__ int swb(int i, int bj) {
  return (i << 5) + (bj ^ ((i >> 2) & 7));
}
__device__ __forceinline__ float ldsw(const float* l, int i, int j) {
  int bj = j >> 2;
  return l[(i << 7) + (((bj ^ ((i >> 2) & 7)) << 2) | (j & 3))];
}

// Straight-line named-scalar macros only (R8 lesson). Now parameterized by
// runtime OI (row-chunk) / TYC (=OI/4) so a 256-thread block covers the
// plane in 4 sequential chunks per thread (#pragma unroll 1 loops).

#define HROW(h, m, lo, hi)                                                     \
  h.x = lo + m.x + m.y; h.y = m.x + m.y + m.z;                                 \
  h.z = m.y + m.z + m.w; h.w = m.z + m.w + hi;

#define FMA4(T, C, M)                                                          \
  T.x += (C) * M.x; T.y += (C) * M.y; T.z += (C) * M.z; T.w += (C) * M.w;

#define BLUR4(T, A, B, Cq)                                                     \
  T.x += c1 * (A.x + B.x + Cq.x); T.y += c1 * (A.y + B.y + Cq.y);              \
  T.z += c1 * (A.z + B.z + Cq.z); T.w += c1 * (A.w + B.w + Cq.w);

#define FLIPL(T, M)                                                            \
  T.x += c2 * M.w; T.y += c2 * M.z; T.z += c2 * M.y; T.w += c2 * M.x;

#define GATHER(L4, L1, OI, TYC) {                                              \
  float4 m, hA, hB, hC; float lo, hi; int ri;                                  \
  /* r=0 */                                                                    \
  ri = ((OI) == 0) ? 1 : (OI) - 1;                                             \
  m = (L4)[swb(ri, tx)]; lo = ldsw((L1), ri, cLo); hi = ldsw((L1), ri, cHi);   \
  HROW(hA, m, lo, hi)                                                          \
  /* r=1 */                                                                    \
  m = (L4)[swb((OI), tx)]; lo = ldsw((L1), (OI), cLo); hi = ldsw((L1), (OI), cHi); \
  FMA4(T0, c0, m)                                                              \
  HROW(hB, m, lo, hi)                                                          \
  /* r=2 */                                                                    \
  m = (L4)[swb((OI)+1, tx)]; lo = ldsw((L1), (OI)+1, cLo); hi = ldsw((L1), (OI)+1, cHi); \
  FMA4(T1, c0, m)                                                              \
  HROW(hC, m, lo, hi)                                                          \
  BLUR4(T0, hA, hB, hC)                                                        \
  /* r=3 */                                                                    \
  m = (L4)[swb((OI)+2, tx)]; lo = ldsw((L1), (OI)+2, cLo); hi = ldsw((L1), (OI)+2, cHi); \
  FMA4(T2, c0, m)                                                              \
  HROW(hA, m, lo, hi)                                                          \
  BLUR4(T1, hB, hC, hA)                                                        \
  /* r=4 */                                                                    \
  m = (L4)[swb((OI)+3, tx)]; lo = ldsw((L1), (OI)+3, cLo); hi = ldsw((L1), (OI)+3, cHi); \
  FMA4(T3, c0, m)                                                              \
  HROW(hB, m, lo, hi)                                                          \
  BLUR4(T2, hC, hA, hB)                                                        \
  /* r=5 */                                                                    \
  ri = ((OI) == 124) ? 126 : (OI) + 4;                                         \
  m = (L4)[swb(ri, tx)]; lo = ldsw((L1), ri, cLo); hi = ldsw((L1), ri, cHi);   \
  HROW(hC, m, lo, hi)                                                          \
  BLUR4(T3, hA, hB, hC)                                                        \
  /* fliplr */                                                                 \
  m = (L4)[swb((OI),   31 - tx)]; FLIPL(T0, m)                                 \
  m = (L4)[swb((OI)+1, 31 - tx)]; FLIPL(T1, m)                                 \
  m = (L4)[swb((OI)+2, 31 - tx)]; FLIPL(T2, m)                                 \
  m = (L4)[swb((OI)+3, 31 - tx)]; FLIPL(T3, m)                                 \
  /* flipud */                                                                 \
  m = (L4)[swb(127 - (OI), tx)]; FMA4(T0, c3, m)                               \
  m = (L4)[swb(126 - (OI), tx)]; FMA4(T1, c3, m)                               \
  m = (L4)[swb(125 - (OI), tx)]; FMA4(T2, c3, m)                               \
  m = (L4)[swb(124 - (OI), tx)]; FMA4(T3, c3, m)                               \
  /* roll(+4,+4) */                                                            \
  m = (L4)[swb(((OI) - 4) & 127, rc)]; FMA4(T0, c4, m)                         \
  m = (L4)[swb(((OI) - 3) & 127, rc)]; FMA4(T1, c4, m)                         \
  m = (L4)[swb(((OI) - 2) & 127, rc)]; FMA4(T2, c4, m)                         \
  m = (L4)[swb(((OI) - 1) & 127, rc)]; FMA4(T3, c4, m)                         \
  /* rot90 k=1: out[i][j] = src[j][127-i] */                                   \
  m = (L4)[swb(oj,     31 - (TYC))];                                           \
  T0.x += c5 * m.w; T1.x += c5 * m.z; T2.x += c5 * m.y; T3.x += c5 * m.x;      \
  m = (L4)[swb(oj + 1, 31 - (TYC))];                                           \
  T0.y += c5 * m.w; T1.y += c5 * m.z; T2.y += c5 * m.y; T3.y += c5 * m.x;      \
  m = (L4)[swb(oj + 2, 31 - (TYC))];                                           \
  T0.z += c5 * m.w; T1.z += c5 * m.z; T2.z += c5 * m.y; T3.z += c5 * m.x;      \
  m = (L4)[swb(oj + 3, 31 - (TYC))];                                           \
  T0.w += c5 * m.w; T1.w += c5 * m.z; T2.w += c5 * m.y; T3.w += c5 * m.x;      \
}

#define LDCF(P, TG) {                                                          \
  const float* cfp = wsf + WS_TAB + ((P) * 4 + (TG)) * 6;                      \
  c0 = cfp[0]; c1 = cfp[1]; c2 = cfp[2]; c3 = cfp[3]; c4 = cfp[4]; c5 = cfp[5]; }

#define SETC(K) {                                                              \
  float cst = wsf[WS_CONST + (K)];                                             \
  T0.x = cst; T0.y = cst; T0.z = cst; T0.w = cst; T1 = T0; T2 = T0; T3 = T0; }

#define STAGE_BN(L4, OI) {                                                     \
  float4 v;                                                                    \
  v = x4[((OI)+0)*32 + tx]; v.x = v.x*sc+sh; v.y = v.y*sc+sh; v.z = v.z*sc+sh; \
  v.w = v.w*sc+sh; (L4)[swb((OI)+0, tx)] = v;                                  \
  v = x4[((OI)+1)*32 + tx]; v.x = v.x*sc+sh; v.y = v.y*sc+sh; v.z = v.z*sc+sh; \
  v.w = v.w*sc+sh; (L4)[swb((OI)+1, tx)] = v;                                  \
  v = x4[((OI)+2)*32 + tx]; v.x = v.x*sc+sh; v.y = v.y*sc+sh; v.z = v.z*sc+sh; \
  v.w = v.w*sc+sh; (L4)[swb((OI)+2, tx)] = v;                                  \
  v = x4[((OI)+3)*32 + tx]; v.x = v.x*sc+sh; v.y = v.y*sc+sh; v.z = v.z*sc+sh; \
  v.w = v.w*sc+sh; (L4)[swb((OI)+3, tx)] = v; }

#define STAGE_OUT(L4, TG, OI) {                                                \
  (L4)[swb((OI)+0, tx)] = out4[(pbase + (TG)*NCH)*4096 + ((OI)+0)*32 + tx];    \
  (L4)[swb((OI)+1, tx)] = out4[(pbase + (TG)*NCH)*4096 + ((OI)+1)*32 + tx];    \
  (L4)[swb((OI)+2, tx)] = out4[(pbase + (TG)*NCH)*4096 + ((OI)+2)*32 + tx];    \
  (L4)[swb((OI)+3, tx)] = out4[(pbase + (TG)*NCH)*4096 + ((OI)+3)*32 + tx]; }

#define WRITEV(TG, OI) {                                                       \
  out4[(pbase + (TG)*NCH)*4096 + ((OI)+0)*32 + tx] = T0;                       \
  out4[(pbase + (TG)*NCH)*4096 + ((OI)+1)*32 + tx] = T1;                       \
  out4[(pbase + (TG)*NCH)*4096 + ((OI)+2)*32 + tx] = T2;                       \
  out4[(pbase + (TG)*NCH)*4096 + ((OI)+3)*32 + tx] = T3; }

#define LOADV(TG, OI) {                                                        \
  T0 = out4[(pbase + (TG)*NCH)*4096 + ((OI)+0)*32 + tx];                       \
  T1 = out4[(pbase + (TG)*NCH)*4096 + ((OI)+1)*32 + tx];                       \
  T2 = out4[(pbase + (TG)*NCH)*4096 + ((OI)+2)*32 + tx];                       \
  T3 = out4[(pbase + (TG)*NCH)*4096 + ((OI)+3)*32 + tx]; }

#define STASHV(L4, OI) {                                                       \
  (L4)[swb((OI)+0, tx)] = T0; (L4)[swb((OI)+1, tx)] = T1;                      \
  (L4)[swb((OI)+2, tx)] = T2; (L4)[swb((OI)+3, tx)] = T3; }

// 256 threads: dodge the 64-VGPR clamp observed for every 1024-thread
// variant (R2-R8). Each thread processes 4 row-chunks (ty+8k). s4/s5 use
// same-thread RMW via out (partial sums) so only T0..T3 is ever live.
__global__ __launch_bounds__(256, 1)
void main_kernel(const float* __restrict__ x,
                 const float* __restrict__ wsf, float* out)
{
  __shared__ float lds[2 * PLANE];        // 128 KB -> 1 block/CU
  float* b0 = lds;
  float* b1 = lds + PLANE;
  float4* l40 = (float4*)b0;
  float4* l41 = (float4*)b1;
  int bx = blockIdx.x;
  int b = bx / NCH, c = bx % NCH;
  int tid = threadIdx.x;
  int ty = tid >> 5, tx = tid & 31;     // ty in 0..7
  int oj = tx << 2;
  int cLo = (tx == 0)  ? 1   : oj - 1;
  int cHi = (tx == 31) ? 126 : oj + 4;
  int rc  = (tx + 31) & 31;
  float4* out4 = (float4*)out;
  const size_t pbase = (size_t)b * 192 + c;
  const float4* x4 = (const float4*)x + (size_t)bx * 4096;
  float sc = wsf[WS_SCALE + c], sh = wsf[WS_SHIFT + c];

  float4 T0, T1, T2, T3;
  float c0, c1, c2, c3, c4, c5;

  // stage s -> buf0
  #pragma unroll 1
  for (int k = 0; k < 4; ++k) {
    int oi = (ty + 8 * k) << 2;
    STAGE_BN(l40, oi);
  }
  __syncthreads();

  // s2 = L(0,0)[s]; stash s2 -> buf1
  #pragma unroll 1
  for (int k = 0; k < 4; ++k) {
    int oi = (ty + 8 * k) << 2; int tyc = ty + 8 * k;
    SETC(0); LDCF(0, 0);
    GATHER(l40, b0, oi, tyc);
    WRITEV(0, oi);
    STASHV(l41, oi);
  }
  __syncthreads();

  // s3 full; s4,s5 partial contributions from s and s2
  #pragma unroll 1
  for (int k = 0; k < 4; ++k) {
    int oi = (ty + 8 * k) << 2; int tyc = ty + 8 * k;
    SETC(1); LDCF(0, 1); GATHER(l40, b0, oi, tyc);
             LDCF(1, 1); GATHER(l41, b1, oi, tyc);
    WRITEV(1, oi);
    SETC(2); LDCF(0, 2); GATHER(l40, b0, oi, tyc);
             LDCF(1, 2); GATHER(l41, b1, oi, tyc);
    WRITEV(2, oi);                          // partial s4
    SETC(3); LDCF(0, 3); GATHER(l40, b0, oi, tyc);
             LDCF(1, 3); GATHER(l41, b1, oi, tyc);
    WRITEV(3, oi);                          // partial s5
  }
  __syncthreads();                          // all buf0 reads done; s3 visible

  // restage s3 -> buf0
  #pragma unroll 1
  for (int k = 0; k < 4; ++k) {
    int oi = (ty + 8 * k) << 2;
    STAGE_OUT(l40, 1, oi);
  }
  __syncthreads();

  // s4 final (+= L(2,2)[s3]); s5 += L(2,3)[s3]   (same-thread RMW via out)
  #pragma unroll 1
  for (int k = 0; k < 4; ++k) {
    int oi = (ty + 8 * k) << 2; int tyc = ty + 8 * k;
    LOADV(2, oi); LDCF(2, 2); GATHER(l40, b0, oi, tyc); WRITEV(2, oi);
    LOADV(3, oi); LDCF(2, 3); GATHER(l40, b0, oi, tyc); WRITEV(3, oi);
  }
  __syncthreads();                          // buf1 reads (s2) long done; s4 visible

  // restage s4 -> buf1
  #pragma unroll 1
  for (int k = 0; k < 4; ++k) {
    int oi = (ty + 8 * k) << 2;
    STAGE_OUT(l41, 2, oi);
  }
  __syncthreads();

  // s5 final (+= L(3,3)[s4])
  #pragma unroll 1
  for (int k = 0; k < 4; ++k) {
    int oi = (ty + 8 * k) << 2; int tyc = ty + 8 * k;
    LOADV(3, oi); LDCF(3, 3); GATHER(l41, b1, oi, tyc); WRITEV(3, oi);
  }
}

extern "C" void kernel_launch(void* const* d_in, const int* in_sizes, int n_in,
                              void* d_out, int out_size, void* d_ws, size_t ws_size,
                              hipStream_t stream) {
  (void)in_sizes; (void)n_in; (void)out_size; (void)ws_size;
  const float* x     = (const float*)d_in[0];
  const float* gamma = (const float*)d_in[1];
  const float* beta  = (const float*)d_in[2];
  const float* a_red = (const float*)d_in[4];   // reference uses alphas_reduce
  float* ws  = (float*)d_ws;
  float* out = (float*)d_out;

  stats_kernel<<<NPLANES, 256, 0, stream>>>(x, ws);
  prep_kernel<<<1, 64, 0, stream>>>(gamma, beta, a_red, ws);
  main_kernel<<<NPLANES, 256, 0, stream>>>(x, ws, out);
}

// Round 10
// 120.617 us; speedup vs baseline: 5.5029x; 1.3925x over previous
//
#include <hip/hip_runtime.h>
#include <math.h>

#define NCH 48
#define NB 16
#define PLANE 16384
#define NPLANES 768

// d_ws float layout
#define WS_PSUM  0
#define WS_PSQ   768
#define WS_SCALE 1536
#define WS_SHIFT 1584
#define WS_TAB   1632   // [src 4][tgt 4][6 coefs]
#define WS_CONST 1728   // [4]

typedef _Float16 h2 __attribute__((ext_vector_type(2)));

// ---------------- stage A: per-plane partial sums ----------------
__global__ __launch_bounds__(256) void stats_kernel(const float* __restrict__ x,
                                                    float* __restrict__ ws) {
  int p = blockIdx.x;
  int t = threadIdx.x;
  const float4* x4 = (const float4*)x + (size_t)p * 4096;
  float s = 0.f, q = 0.f;
  #pragma unroll
  for (int k = 0; k < 16; ++k) {
    float4 v = x4[k * 256 + t];
    s += v.x + v.y + v.z + v.w;
    q += v.x * v.x + v.y * v.y + v.z * v.z + v.w * v.w;
  }
  #pragma unroll
  for (int off = 32; off > 0; off >>= 1) {
    s += __shfl_xor(s, off, 64);
    q += __shfl_xor(q, off, 64);
  }
  __shared__ float red[8];
  int wid = t >> 6, lane = t & 63;
  if (lane == 0) { red[wid] = s; red[4 + wid] = q; }
  __syncthreads();
  if (t == 0) {
    ws[WS_PSUM + p] = red[0] + red[1] + red[2] + red[3];
    ws[WS_PSQ  + p] = red[4] + red[5] + red[6] + red[7];
  }
}

// ---------------- stage B: BN params + merged weight table ----------------
__global__ void prep_kernel(const float* __restrict__ gamma, const float* __restrict__ beta,
                            const float* __restrict__ alphas, float* __restrict__ ws) {
  int t = threadIdx.x;
  if (t < NCH) {
    float s = 0.f, q = 0.f;
    for (int b = 0; b < NB; ++b) {
      s += ws[WS_PSUM + b * NCH + t];
      q += ws[WS_PSQ  + b * NCH + t];
    }
    const float inv = 1.0f / ((float)NB * PLANE);
    float mean = s * inv;
    float var  = q * inv - mean * mean;
    float sc = gamma[t] * rsqrtf(var + 1e-5f);
    ws[WS_SCALE + t] = sc;
    ws[WS_SHIFT + t] = beta[t] - mean * sc;
  }
  if (t == 0) {
    float w[14][7];
    for (int r = 0; r < 14; ++r) {
      float m = -1e30f;
      for (int k = 0; k < 7; ++k) m = fmaxf(m, alphas[r * 7 + k]);
      float sum = 0.f;
      for (int k = 0; k < 7; ++k) { float e = expf(alphas[r * 7 + k] - m); w[r][k] = e; sum += e; }
      float is = 1.0f / sum;
      for (int k = 0; k < 7; ++k) w[r][k] *= is;
    }
    for (int i = 0; i < 96; ++i) ws[WS_TAB + i] = 0.f;
    for (int i = 0; i < 4;  ++i) ws[WS_CONST + i] = 0.f;
    const int map[14][2] = {
      {0,0},{0,0},
      {0,1},{0,1},{1,1},
      {0,2},{0,2},{1,2},{2,2},
      {0,3},{0,3},{1,3},{2,3},{3,3}
    };
    for (int r = 0; r < 14; ++r) {
      int p = map[r][0], tg = map[r][1];
      float* cf = ws + WS_TAB + (p * 4 + tg) * 6;
      cf[0] += w[r][0] - w[r][2];       // identity
      cf[1] += w[r][1] * (1.0f / 9.0f); // blur (/9 folded)
      cf[2] += w[r][3];                 // fliplr
      cf[3] += w[r][4];                 // flipud
      cf[4] += w[r][5];                 // roll(+4,+4)
      cf[5] += w[r][6];                 // rot90
      ws[WS_CONST + tg] += w[r][2];     // constant w2
    }
  }
}

// ---------------- main fused kernel ----------------
// fp16 LDS planes (R9 post-mortem: 128 KB fp32 LDS -> 1 block/CU -> 1
// wave/SIMD -> latency-bound at VALUBusy 25%). Two fp16 planes = 64 KB ->
// 2 blocks/CU. Accumulation and all global I/O remain fp32; fp16 rounding
// adds ~0.01-0.03 absmax (threshold 0.194, fp32 version measured 0.031).
//
// Layout: plane = 128 rows x 64 h2 (8192 h2, 32 KB). Quad q in 0..31 = 8B
// (4 halves) at h2 indices (i<<6)+(q'<<1), q' = q ^ (i&31) XOR-swizzle so
// rot90's column-pattern reads spread across banks (linear layout would be
// 32-way conflicted: bank depends only on quad, not row).

__device__ __forceinline__ float ldshw(const h2* L, int i, int j) {
  int q = (j >> 2) ^ (i & 31);
  h2 p = L[(i << 6) + (q << 1) + ((j & 2) >> 1)];
  return (j & 1) ? (float)p.y : (float)p.x;
}

#define RDQ(L, I, B, M) {                                                      \
  int q_ = (B) ^ ((I) & 31);                                                   \
  h2 p0_ = (L)[((I) << 6) + (q_ << 1)];                                        \
  h2 p1_ = (L)[((I) << 6) + (q_ << 1) + 1];                                    \
  M.x = (float)p0_.x; M.y = (float)p0_.y;                                      \
  M.z = (float)p1_.x; M.w = (float)p1_.y; }

#define WRQ(L, I, B, V) {                                                      \
  int q_ = (B) ^ ((I) & 31);                                                   \
  h2 p0_, p1_;                                                                 \
  p0_.x = (_Float16)V.x; p0_.y = (_Float16)V.y;                                \
  p1_.x = (_Float16)V.z; p1_.y = (_Float16)V.w;                                \
  (L)[((I) << 6) + (q_ << 1)] = p0_;                                           \
  (L)[((I) << 6) + (q_ << 1) + 1] = p1_; }

#define HROW(h, m, lo, hi)                                                     \
  h.x = lo + m.x + m.y; h.y = m.x + m.y + m.z;                                 \
  h.z = m.y + m.z + m.w; h.w = m.z + m.w + hi;

#define FMA4(T, C, M)                                                          \
  T.x += (C) * M.x; T.y += (C) * M.y; T.z += (C) * M.z; T.w += (C) * M.w;

#define BLUR4(T, A, B, Cq)                                                     \
  T.x += c1 * (A.x + B.x + Cq.x); T.y += c1 * (A.y + B.y + Cq.y);              \
  T.z += c1 * (A.z + B.z + Cq.z); T.w += c1 * (A.w + B.w + Cq.w);

#define FLIPL(T, M)                                                            \
  T.x += c2 * M.w; T.y += c2 * M.z; T.z += c2 * M.y; T.w += c2 * M.x;

#define GATHER(L, OI, TYC) {                                                   \
  float4 m, hA, hB, hC; float lo, hi; int ri;                                  \
  /* r=0 */                                                                    \
  ri = ((OI) == 0) ? 1 : (OI) - 1;                                             \
  RDQ(L, ri, tx, m) lo = ldshw(L, ri, cLo); hi = ldshw(L, ri, cHi);            \
  HROW(hA, m, lo, hi)                                                          \
  /* r=1 */                                                                    \
  RDQ(L, (OI), tx, m) lo = ldshw(L, (OI), cLo); hi = ldshw(L, (OI), cHi);      \
  FMA4(T0, c0, m)                                                              \
  HROW(hB, m, lo, hi)                                                          \
  /* r=2 */                                                                    \
  RDQ(L, (OI)+1, tx, m) lo = ldshw(L, (OI)+1, cLo); hi = ldshw(L, (OI)+1, cHi);\
  FMA4(T1, c0, m)                                                              \
  HROW(hC, m, lo, hi)                                                          \
  BLUR4(T0, hA, hB, hC)                                                        \
  /* r=3 */                                                                    \
  RDQ(L, (OI)+2, tx, m) lo = ldshw(L, (OI)+2, cLo); hi = ldshw(L, (OI)+2, cHi);\
  FMA4(T2, c0, m)                                                              \
  HROW(hA, m, lo, hi)                                                          \
  BLUR4(T1, hB, hC, hA)                                                        \
  /* r=4 */                                                                    \
  RDQ(L, (OI)+3, tx, m) lo = ldshw(L, (OI)+3, cLo); hi = ldshw(L, (OI)+3, cHi);\
  FMA4(T3, c0, m)                                                              \
  HROW(hB, m, lo, hi)                                                          \
  BLUR4(T2, hC, hA, hB)                                                        \
  /* r=5 */                                                                    \
  ri = ((OI) == 124) ? 126 : (OI) + 4;                                         \
  RDQ(L, ri, tx, m) lo = ldshw(L, ri, cLo); hi = ldshw(L, ri, cHi);            \
  HROW(hC, m, lo, hi)                                                          \
  BLUR4(T3, hA, hB, hC)                                                        \
  /* fliplr */                                                                 \
  RDQ(L, (OI),   31 - tx, m) FLIPL(T0, m)                                      \
  RDQ(L, (OI)+1, 31 - tx, m) FLIPL(T1, m)                                      \
  RDQ(L, (OI)+2, 31 - tx, m) FLIPL(T2, m)                                      \
  RDQ(L, (OI)+3, 31 - tx, m) FLIPL(T3, m)                                      \
  /* flipud */                                                                 \
  RDQ(L, 127 - (OI), tx, m) FMA4(T0, c3, m)                                    \
  RDQ(L, 126 - (OI), tx, m) FMA4(T1, c3, m)                                    \
  RDQ(L, 125 - (OI), tx, m) FMA4(T2, c3, m)                                    \
  RDQ(L, 124 - (OI), tx, m) FMA4(T3, c3, m)                                    \
  /* roll(+4,+4) */                                                            \
  RDQ(L, ((OI) - 4) & 127, rc, m) FMA4(T0, c4, m)                              \
  RDQ(L, ((OI) - 3) & 127, rc, m) FMA4(T1, c4, m)                              \
  RDQ(L, ((OI) - 2) & 127, rc, m) FMA4(T2, c4, m)                              \
  RDQ(L, ((OI) - 1) & 127, rc, m) FMA4(T3, c4, m)                              \
  /* rot90 k=1: out[i][j] = src[j][127-i] */                                   \
  RDQ(L, oj,     31 - (TYC), m)                                                \
  T0.x += c5 * m.w; T1.x += c5 * m.z; T2.x += c5 * m.y; T3.x += c5 * m.x;      \
  RDQ(L, oj + 1, 31 - (TYC), m)                                                \
  T0.y += c5 * m.w; T1.y += c5 * m.z; T2.y += c5 * m.y; T3.y += c5 * m.x;      \
  RDQ(L, oj + 2, 31 - (TYC), m)                                                \
  T0.z += c5 * m.w; T1.z += c5 * m.z; T2.z += c5 * m.y; T3.z += c5 * m.x;      \
  RDQ(L, oj + 3, 31 - (TYC), m)                                                \
  T0.w += c5 * m.w; T1.w += c5 * m.z; T2.w += c5 * m.y; T3.w += c5 * m.x;      \
}

#define LDCF(P, TG) {                                                          \
  const float* cfp = wsf + WS_TAB + ((P) * 4 + (TG)) * 6;                      \
  c0 = cfp[0]; c1 = cfp[1]; c2 = cfp[2]; c3 = cfp[3]; c4 = cfp[4]; c5 = cfp[5]; }

#define SETC(K) {                                                              \
  float cst = wsf[WS_CONST + (K)];                                             \
  T0.x = cst; T0.y = cst; T0.z = cst; T0.w = cst; T1 = T0; T2 = T0; T3 = T0; }

#define STAGE_BN(L, OI) {                                                      \
  float4 v;                                                                    \
  v = x4[((OI)+0)*32 + tx]; v.x = v.x*sc+sh; v.y = v.y*sc+sh; v.z = v.z*sc+sh; \
  v.w = v.w*sc+sh; WRQ(L, (OI)+0, tx, v)                                       \
  v = x4[((OI)+1)*32 + tx]; v.x = v.x*sc+sh; v.y = v.y*sc+sh; v.z = v.z*sc+sh; \
  v.w = v.w*sc+sh; WRQ(L, (OI)+1, tx, v)                                       \
  v = x4[((OI)+2)*32 + tx]; v.x = v.x*sc+sh; v.y = v.y*sc+sh; v.z = v.z*sc+sh; \
  v.w = v.w*sc+sh; WRQ(L, (OI)+2, tx, v)                                       \
  v = x4[((OI)+3)*32 + tx]; v.x = v.x*sc+sh; v.y = v.y*sc+sh; v.z = v.z*sc+sh; \
  v.w = v.w*sc+sh; WRQ(L, (OI)+3, tx, v) }

#define STAGE_OUT(L, TG, OI) {                                                 \
  float4 v;                                                                    \
  v = out4[(pbase + (TG)*NCH)*4096 + ((OI)+0)*32 + tx]; WRQ(L, (OI)+0, tx, v)  \
  v = out4[(pbase + (TG)*NCH)*4096 + ((OI)+1)*32 + tx]; WRQ(L, (OI)+1, tx, v)  \
  v = out4[(pbase + (TG)*NCH)*4096 + ((OI)+2)*32 + tx]; WRQ(L, (OI)+2, tx, v)  \
  v = out4[(pbase + (TG)*NCH)*4096 + ((OI)+3)*32 + tx]; WRQ(L, (OI)+3, tx, v) }

#define WRITEV(TG, OI) {                                                       \
  out4[(pbase + (TG)*NCH)*4096 + ((OI)+0)*32 + tx] = T0;                       \
  out4[(pbase + (TG)*NCH)*4096 + ((OI)+1)*32 + tx] = T1;                       \
  out4[(pbase + (TG)*NCH)*4096 + ((OI)+2)*32 + tx] = T2;                       \
  out4[(pbase + (TG)*NCH)*4096 + ((OI)+3)*32 + tx] = T3; }

#define LOADV(TG, OI) {                                                        \
  T0 = out4[(pbase + (TG)*NCH)*4096 + ((OI)+0)*32 + tx];                       \
  T1 = out4[(pbase + (TG)*NCH)*4096 + ((OI)+1)*32 + tx];                       \
  T2 = out4[(pbase + (TG)*NCH)*4096 + ((OI)+2)*32 + tx];                       \
  T3 = out4[(pbase + (TG)*NCH)*4096 + ((OI)+3)*32 + tx]; }

#define STASHV(L, OI) {                                                        \
  WRQ(L, (OI)+0, tx, T0) WRQ(L, (OI)+1, tx, T1)                                \
  WRQ(L, (OI)+2, tx, T2) WRQ(L, (OI)+3, tx, T3) }

__global__ __launch_bounds__(256, 1)
void main_kernel(const float* __restrict__ x,
                 const float* __restrict__ wsf, float* out)
{
  __shared__ h2 lds[2 * 8192];            // 64 KB total -> 2 blocks/CU
  h2* h0 = lds;
  h2* h1 = lds + 8192;
  int bx = blockIdx.x;
  int b = bx / NCH, c = bx % NCH;
  int tid = threadIdx.x;
  int ty = tid >> 5, tx = tid & 31;       // ty in 0..7
  int oj = tx << 2;
  int cLo = (tx == 0)  ? 1   : oj - 1;
  int cHi = (tx == 31) ? 126 : oj + 4;
  int rc  = (tx + 31) & 31;
  float4* out4 = (float4*)out;
  const size_t pbase = (size_t)b * 192 + c;
  const float4* x4 = (const float4*)x + (size_t)bx * 4096;
  float sc = wsf[WS_SCALE + c], sh = wsf[WS_SHIFT + c];

  float4 T0, T1, T2, T3;
  float c0, c1, c2, c3, c4, c5;

  // stage s -> buf0
  #pragma unroll 1
  for (int k = 0; k < 4; ++k) {
    int oi = (ty + 8 * k) << 2;
    STAGE_BN(h0, oi);
  }
  __syncthreads();

  // s2 = L(0,0)[s]; stash s2 -> buf1
  #pragma unroll 1
  for (int k = 0; k < 4; ++k) {
    int oi = (ty + 8 * k) << 2; int tyc = ty + 8 * k;
    SETC(0); LDCF(0, 0);
    GATHER(h0, oi, tyc);
    WRITEV(0, oi);
    STASHV(h1, oi);
  }
  __syncthreads();

  // s3 full; s4,s5 partial contributions from s and s2
  #pragma unroll 1
  for (int k = 0; k < 4; ++k) {
    int oi = (ty + 8 * k) << 2; int tyc = ty + 8 * k;
    SETC(1); LDCF(0, 1); GATHER(h0, oi, tyc);
             LDCF(1, 1); GATHER(h1, oi, tyc);
    WRITEV(1, oi);
    SETC(2); LDCF(0, 2); GATHER(h0, oi, tyc);
             LDCF(1, 2); GATHER(h1, oi, tyc);
    WRITEV(2, oi);                          // partial s4
    SETC(3); LDCF(0, 3); GATHER(h0, oi, tyc);
             LDCF(1, 3); GATHER(h1, oi, tyc);
    WRITEV(3, oi);                          // partial s5
  }
  __syncthreads();                          // all buf0 reads done; s3 visible

  // restage s3 -> buf0
  #pragma unroll 1
  for (int k = 0; k < 4; ++k) {
    int oi = (ty + 8 * k) << 2;
    STAGE_OUT(h0, 1, oi);
  }
  __syncthreads();

  // s4 final (+= L(2,2)[s3]); s5 += L(2,3)[s3]   (same-thread RMW via out)
  #pragma unroll 1
  for (int k = 0; k < 4; ++k) {
    int oi = (ty + 8 * k) << 2; int tyc = ty + 8 * k;
    LOADV(2, oi); LDCF(2, 2); GATHER(h0, oi, tyc); WRITEV(2, oi);
    LOADV(3, oi); LDCF(2, 3); GATHER(h0, oi, tyc); WRITEV(3, oi);
  }
  __syncthreads();                          // buf1 reads (s2) long done; s4 visible

  // restage s4 -> buf1
  #pragma unroll 1
  for (int k = 0; k < 4; ++k) {
    int oi = (ty + 8 * k) << 2;
    STAGE_OUT(h1, 2, oi);
  }
  __syncthreads();

  // s5 final (+= L(3,3)[s4])
  #pragma unroll 1
  for (int k = 0; k < 4; ++k) {
    int oi = (ty + 8 * k) << 2; int tyc = ty + 8 * k;
    LOADV(3, oi); LDCF(3, 3); GATHER(h1, oi, tyc); WRITEV(3, oi);
  }
}

extern "C" void kernel_launch(void* const* d_in, const int* in_sizes, int n_in,
                              void* d_out, int out_size, void* d_ws, size_t ws_size,
                              hipStream_t stream) {
  (void)in_sizes; (void)n_in; (void)out_size; (void)ws_size;
  const float* x     = (const float*)d_in[0];
  const float* gamma = (const float*)d_in[1];
  const float* beta  = (const float*)d_in[2];
  const float* a_red = (const float*)d_in[4];   // reference uses alphas_reduce
  float* ws  = (float*)d_ws;
  float* out = (float*)d_out;

  stats_kernel<<<NPLANES, 256, 0, stream>>>(x, ws);
  prep_kernel<<<1, 64, 0, stream>>>(gamma, beta, a_red, ws);
  main_kernel<<<NPLANES, 256, 0, stream>>>(x, ws, out);
}